// Round 1
// baseline (828.120 us; speedup 1.0000x reference)
//
#include <hip/hip_runtime.h>

#define N_USER 50000
#define N_ITEM 50000
#define N_EDGE 1600000
#define D 64

// ---------------------------------------------------------------------------
// Kernel 1: dual GEMM. out1 = feat@W1 + b1 (into ws), out2 = feat@W2 + b2
// (self-loop term, straight into d_out). 16 rows per block, W staged in LDS.
// ---------------------------------------------------------------------------
__global__ __launch_bounds__(256) void gemm_dual(
    const float* __restrict__ feat,
    const float* __restrict__ W1, const float* __restrict__ b1, float* __restrict__ out1,
    const float* __restrict__ W2, const float* __restrict__ b2, float* __restrict__ out2,
    int nrows)
{
    __shared__ float sW1[64][64];
    __shared__ float sW2[64][64];
    __shared__ float sF[16][64];
    __shared__ float sb1[64], sb2[64];
    const int tid = threadIdx.x;

    for (int i = tid; i < 4096; i += 256) {
        sW1[i >> 6][i & 63] = W1[i];
        sW2[i >> 6][i & 63] = W2[i];
    }
    if (tid < 64) { sb1[tid] = b1[tid]; sb2[tid] = b2[tid]; }

    const int row0 = blockIdx.x * 16;
    for (int i = tid; i < 1024; i += 256) {
        int r = row0 + (i >> 6);
        sF[i >> 6][i & 63] = (r < nrows) ? feat[(size_t)r * D + (i & 63)] : 0.0f;
    }
    __syncthreads();

    const int c = tid & 63;   // output column
    const int r = tid >> 6;   // handles local rows r, r+4, r+8, r+12
    float a0 = 0.f, a1 = 0.f, a2 = 0.f, a3 = 0.f;
    float l0 = 0.f, l1 = 0.f, l2 = 0.f, l3 = 0.f;
    #pragma unroll
    for (int k = 0; k < 64; ++k) {
        float w1 = sW1[k][c], w2 = sW2[k][c];
        float f0 = sF[r][k], f1 = sF[r + 4][k], f2 = sF[r + 8][k], f3 = sF[r + 12][k];
        a0 += f0 * w1; a1 += f1 * w1; a2 += f2 * w1; a3 += f3 * w1;
        l0 += f0 * w2; l1 += f1 * w2; l2 += f2 * w2; l3 += f3 * w2;
    }
    const float bb1 = sb1[c], bb2 = sb2[c];
    int rr;
    rr = row0 + r;      if (rr < nrows) { out1[(size_t)rr * D + c] = a0 + bb1; out2[(size_t)rr * D + c] = l0 + bb2; }
    rr = row0 + r + 4;  if (rr < nrows) { out1[(size_t)rr * D + c] = a1 + bb1; out2[(size_t)rr * D + c] = l1 + bb2; }
    rr = row0 + r + 8;  if (rr < nrows) { out1[(size_t)rr * D + c] = a2 + bb1; out2[(size_t)rr * D + c] = l2 + bb2; }
    rr = row0 + r + 12; if (rr < nrows) { out1[(size_t)rr * D + c] = a3 + bb1; out2[(size_t)rr * D + c] = l3 + bb2; }
}

// ---------------------------------------------------------------------------
// Kernel 2: per-dst degree histograms for both edge types.
// ---------------------------------------------------------------------------
__global__ void hist_kernel(const int* __restrict__ rate_dst, const int* __restrict__ rev_dst,
                            int* __restrict__ degI, int* __restrict__ degU, int n)
{
    for (int e = blockIdx.x * blockDim.x + threadIdx.x; e < n; e += gridDim.x * blockDim.x) {
        atomicAdd(&degI[rate_dst[e]], 1);
        atomicAdd(&degU[rev_dst[e]], 1);
    }
}

// ---------------------------------------------------------------------------
// Kernel 3: exclusive scan of degrees -> offsets (+1 sentinel) and cursors.
// grid = 2 blocks (block 0: item, block 1: user), 1024 threads each.
// ---------------------------------------------------------------------------
__global__ __launch_bounds__(1024) void scan_kernel(
    const int* __restrict__ degI, int* __restrict__ offI, int* __restrict__ curI,
    const int* __restrict__ degU, int* __restrict__ offU, int* __restrict__ curU, int n)
{
    const int* deg = (blockIdx.x == 0) ? degI : degU;
    int* off       = (blockIdx.x == 0) ? offI : offU;
    int* cur       = (blockIdx.x == 0) ? curI : curU;

    __shared__ int s[1024];
    __shared__ int carry;
    if (threadIdx.x == 0) carry = 0;
    __syncthreads();

    for (int base = 0; base < n; base += 1024) {
        int i = base + threadIdx.x;
        int v = (i < n) ? deg[i] : 0;
        s[threadIdx.x] = v;
        __syncthreads();
        for (int o = 1; o < 1024; o <<= 1) {
            int t = (threadIdx.x >= o) ? s[threadIdx.x - o] : 0;
            __syncthreads();
            s[threadIdx.x] += t;
            __syncthreads();
        }
        int excl = s[threadIdx.x] - v;
        if (i < n) { int o = carry + excl; off[i] = o; cur[i] = o; }
        __syncthreads();
        if (threadIdx.x == 1023) carry += s[1023];
        __syncthreads();
    }
    if (threadIdx.x == 0) off[n] = carry;
}

// ---------------------------------------------------------------------------
// Kernel 4: reorder edges into dst-sorted order (store src index only).
// ---------------------------------------------------------------------------
__global__ void reorder_kernel(const int* __restrict__ rate_src, const int* __restrict__ rate_dst,
                               const int* __restrict__ rev_src, const int* __restrict__ rev_dst,
                               int* __restrict__ curI, int* __restrict__ curU,
                               int* __restrict__ srtI, int* __restrict__ srtU, int n)
{
    for (int e = blockIdx.x * blockDim.x + threadIdx.x; e < n; e += gridDim.x * blockDim.x) {
        int p = atomicAdd(&curI[rate_dst[e]], 1);
        srtI[p] = rate_src[e];
        int q = atomicAdd(&curU[rev_dst[e]], 1);
        srtU[q] = rev_src[e];
    }
}

// ---------------------------------------------------------------------------
// Kernel 5: segment mean + add into loop term already in d_out.
// 16 lanes per dst node, float4 per lane (one 256B Wh row per edge iter).
// Node id g: [0,50000) = users (rev etype), [50000,100000) = items (rate).
// ---------------------------------------------------------------------------
__global__ __launch_bounds__(256) void aggregate_kernel(
    const float4* __restrict__ WhU,  // Wh_rev  (item-sourced msgs -> users)
    const float4* __restrict__ WhI,  // Wh_rate (user-sourced msgs -> items)
    const int* __restrict__ offU, const int* __restrict__ srtU,
    const int* __restrict__ offI, const int* __restrict__ srtI,
    float4* __restrict__ out)
{
    int g = blockIdx.x * 16 + (threadIdx.x >> 4);
    if (g >= N_USER + N_ITEM) return;
    const int lane = threadIdx.x & 15;

    const bool isUser = (g < N_USER);
    const int d = isUser ? g : g - N_USER;
    const float4* __restrict__ Wh = isUser ? WhU : WhI;
    const int* __restrict__ off   = isUser ? offU : offI;
    const int* __restrict__ srt   = isUser ? srtU : srtI;

    const int start = off[d];
    const int end   = off[d + 1];

    float4 acc = make_float4(0.f, 0.f, 0.f, 0.f);
    for (int e = start; e < end; ++e) {
        int s = srt[e];
        float4 v = Wh[(size_t)s * 16 + lane];
        acc.x += v.x; acc.y += v.y; acc.z += v.z; acc.w += v.w;
    }
    const int cnt = end - start;
    const float inv = 1.0f / (float)(cnt > 0 ? cnt : 1);

    float4* o = out + (size_t)g * 16 + lane;
    float4 curv = *o;
    curv.x += acc.x * inv; curv.y += acc.y * inv;
    curv.z += acc.z * inv; curv.w += acc.w * inv;
    *o = curv;
}

// ---------------------------------------------------------------------------
extern "C" void kernel_launch(void* const* d_in, const int* in_sizes, int n_in,
                              void* d_out, int out_size, void* d_ws, size_t ws_size,
                              hipStream_t stream)
{
    const float* user_feat = (const float*)d_in[0];
    const float* item_feat = (const float*)d_in[1];
    const int*   rate_src  = (const int*)d_in[2];
    const int*   rate_dst  = (const int*)d_in[3];
    const int*   rev_src   = (const int*)d_in[4];
    const int*   rev_dst   = (const int*)d_in[5];
    const float* W_rate    = (const float*)d_in[6];
    const float* b_rate    = (const float*)d_in[7];
    const float* W_rev     = (const float*)d_in[8];
    const float* b_rev     = (const float*)d_in[9];
    const float* loop_w    = (const float*)d_in[10];
    const float* h_bias    = (const float*)d_in[11];
    float* out = (float*)d_out;

    // workspace layout (~40 MB)
    char* p = (char*)d_ws;
    float* Wh_rate = (float*)p; p += (size_t)N_USER * D * sizeof(float);
    float* Wh_rev  = (float*)p; p += (size_t)N_ITEM * D * sizeof(float);
    int* srtI = (int*)p; p += (size_t)N_EDGE * sizeof(int);
    int* srtU = (int*)p; p += (size_t)N_EDGE * sizeof(int);
    int* degI = (int*)p; p += (size_t)N_ITEM * sizeof(int);
    int* degU = (int*)p; p += (size_t)N_USER * sizeof(int);
    int* offI = (int*)p; p += (size_t)(N_ITEM + 1) * sizeof(int);
    int* offU = (int*)p; p += (size_t)(N_USER + 1) * sizeof(int);
    int* curI = (int*)p; p += (size_t)N_ITEM * sizeof(int);
    int* curU = (int*)p; p += (size_t)N_USER * sizeof(int);

    // zero the degree histograms (degI/degU are contiguous)
    hipMemsetAsync(degI, 0, (size_t)(N_ITEM + N_USER) * sizeof(int), stream);

    // 1) dual GEMMs: Wh_etype into ws, loop term + bias into d_out
    gemm_dual<<<(N_USER + 15) / 16, 256, 0, stream>>>(
        user_feat, W_rate, b_rate, Wh_rate, loop_w, h_bias, out, N_USER);
    gemm_dual<<<(N_ITEM + 15) / 16, 256, 0, stream>>>(
        item_feat, W_rev, b_rev, Wh_rev, loop_w, h_bias, out + (size_t)N_USER * D, N_ITEM);

    // 2) degree histograms
    hist_kernel<<<1024, 256, 0, stream>>>(rate_dst, rev_dst, degI, degU, N_EDGE);

    // 3) exclusive scan -> offsets + cursors (one block per ntype)
    scan_kernel<<<2, 1024, 0, stream>>>(degI, offI, curI, degU, offU, curU, N_ITEM);

    // 4) dst-sorted src-index lists
    reorder_kernel<<<1024, 256, 0, stream>>>(
        rate_src, rate_dst, rev_src, rev_dst, curI, curU, srtI, srtU, N_EDGE);

    // 5) segment mean + loop-term add
    aggregate_kernel<<<(N_USER + N_ITEM + 15) / 16, 256, 0, stream>>>(
        (const float4*)Wh_rev, (const float4*)Wh_rate, offU, srtU, offI, srtI,
        (float4*)out);
}

// Round 2
// 653.811 us; speedup vs baseline: 1.2666x; 1.2666x over previous
//
#include <hip/hip_runtime.h>

#define N_USER 50000
#define N_ITEM 50000
#define N_NODE 50000
#define N_EDGE 1600000
#define D 64

#define NB 49            // ceil(50000/1024) scan blocks per ntype
#define BUCKET_SHIFT 11
#define N_BUCKET 25      // ceil(50000/2048)
#define BIN_CHUNK 4096   // edges per bin block (16/thread)
#define SC_M 32          // scatter stripes per xcd-group

// ---------------------------------------------------------------------------
// Kernel 1: dual GEMM. out1 = feat@W1 + b1 (into ws), out2 = feat@W2 + b2
// (self-loop term, straight into d_out). 16 rows per block, W staged in LDS.
// ---------------------------------------------------------------------------
__global__ __launch_bounds__(256) void gemm_dual(
    const float* __restrict__ feat,
    const float* __restrict__ W1, const float* __restrict__ b1, float* __restrict__ out1,
    const float* __restrict__ W2, const float* __restrict__ b2, float* __restrict__ out2,
    int nrows)
{
    __shared__ float sW1[64][64];
    __shared__ float sW2[64][64];
    __shared__ float sF[16][64];
    __shared__ float sb1[64], sb2[64];
    const int tid = threadIdx.x;

    for (int i = tid; i < 4096; i += 256) {
        sW1[i >> 6][i & 63] = W1[i];
        sW2[i >> 6][i & 63] = W2[i];
    }
    if (tid < 64) { sb1[tid] = b1[tid]; sb2[tid] = b2[tid]; }

    const int row0 = blockIdx.x * 16;
    for (int i = tid; i < 1024; i += 256) {
        int r = row0 + (i >> 6);
        sF[i >> 6][i & 63] = (r < nrows) ? feat[(size_t)r * D + (i & 63)] : 0.0f;
    }
    __syncthreads();

    const int c = tid & 63;   // output column
    const int r = tid >> 6;   // handles local rows r, r+4, r+8, r+12
    float a0 = 0.f, a1 = 0.f, a2 = 0.f, a3 = 0.f;
    float l0 = 0.f, l1 = 0.f, l2 = 0.f, l3 = 0.f;
    #pragma unroll
    for (int k = 0; k < 64; ++k) {
        float w1 = sW1[k][c], w2 = sW2[k][c];
        float f0 = sF[r][k], f1 = sF[r + 4][k], f2 = sF[r + 8][k], f3 = sF[r + 12][k];
        a0 += f0 * w1; a1 += f1 * w1; a2 += f2 * w1; a3 += f3 * w1;
        l0 += f0 * w2; l1 += f1 * w2; l2 += f2 * w2; l3 += f3 * w2;
    }
    const float bb1 = sb1[c], bb2 = sb2[c];
    int rr;
    rr = row0 + r;      if (rr < nrows) { out1[(size_t)rr * D + c] = a0 + bb1; out2[(size_t)rr * D + c] = l0 + bb2; }
    rr = row0 + r + 4;  if (rr < nrows) { out1[(size_t)rr * D + c] = a1 + bb1; out2[(size_t)rr * D + c] = l1 + bb2; }
    rr = row0 + r + 8;  if (rr < nrows) { out1[(size_t)rr * D + c] = a2 + bb1; out2[(size_t)rr * D + c] = l2 + bb2; }
    rr = row0 + r + 12; if (rr < nrows) { out1[(size_t)rr * D + c] = a3 + bb1; out2[(size_t)rr * D + c] = l3 + bb2; }
}

// ---------------------------------------------------------------------------
// Kernel 2: per-dst degree histograms for both edge types.
// ---------------------------------------------------------------------------
__global__ void hist_kernel(const int* __restrict__ rate_dst, const int* __restrict__ rev_dst,
                            int* __restrict__ degI, int* __restrict__ degU, int n)
{
    for (int e = blockIdx.x * blockDim.x + threadIdx.x; e < n; e += gridDim.x * blockDim.x) {
        atomicAdd(&degI[rate_dst[e]], 1);
        atomicAdd(&degU[rev_dst[e]], 1);
    }
}

// ---------------------------------------------------------------------------
// Parallel 3-kernel exclusive scan. blockIdx.y selects ntype (0=item,1=user).
// ---------------------------------------------------------------------------
__global__ __launch_bounds__(1024) void scanA(
    const int* __restrict__ degI_, int* __restrict__ offI_,
    const int* __restrict__ degU_, int* __restrict__ offU_,
    int* __restrict__ bsums)
{
    const int* deg = blockIdx.y ? degU_ : degI_;
    int* off       = blockIdx.y ? offU_ : offI_;
    __shared__ int s[1024];
    int i = blockIdx.x * 1024 + threadIdx.x;
    int v = (i < N_NODE) ? deg[i] : 0;
    s[threadIdx.x] = v;
    __syncthreads();
    for (int o = 1; o < 1024; o <<= 1) {
        int t = (threadIdx.x >= o) ? s[threadIdx.x - o] : 0;
        __syncthreads();
        s[threadIdx.x] += t;
        __syncthreads();
    }
    if (i < N_NODE) off[i] = s[threadIdx.x] - v;     // block-local exclusive
    if (threadIdx.x == 1023) bsums[blockIdx.y * NB + blockIdx.x] = s[1023];
}

__global__ void scanB(int* __restrict__ bsums, int* __restrict__ offI_, int* __restrict__ offU_)
{
    int t = threadIdx.x;
    if (t < 2) {
        int run = 0;
        for (int j = 0; j < NB; ++j) { int v = bsums[t * NB + j]; bsums[t * NB + j] = run; run += v; }
        if (t == 0) offI_[N_NODE] = run; else offU_[N_NODE] = run;
    }
}

__global__ __launch_bounds__(1024) void scanC(
    int* __restrict__ offI_, int* __restrict__ curI_, int* __restrict__ bcurI_,
    int* __restrict__ offU_, int* __restrict__ curU_, int* __restrict__ bcurU_,
    const int* __restrict__ bsums)
{
    int* off  = blockIdx.y ? offU_ : offI_;
    int* cur  = blockIdx.y ? curU_ : curI_;
    int* bcur = blockIdx.y ? bcurU_ : bcurI_;
    int i = blockIdx.x * 1024 + threadIdx.x;
    if (i < N_NODE) {
        int v = off[i] + bsums[blockIdx.y * NB + blockIdx.x];
        off[i] = v;
        cur[i] = v;
        if ((i & ((1 << BUCKET_SHIFT) - 1)) == 0) bcur[i >> BUCKET_SHIFT] = v;  // bucket base cursor
    }
}

// ---------------------------------------------------------------------------
// Phase 1: bin edges by dst>>11 into bucket-contiguous packed array.
// pack = (dst<<16)|src (both < 65536). LDS hist -> per-block bucket
// reservations -> window-contiguous writes (L2-combinable).
// ---------------------------------------------------------------------------
__global__ __launch_bounds__(256) void bin_kernel(
    const int* __restrict__ srcA, const int* __restrict__ dstA,
    unsigned* __restrict__ binA, int* __restrict__ bcurA,
    const int* __restrict__ srcB, const int* __restrict__ dstB,
    unsigned* __restrict__ binB, int* __restrict__ bcurB)
{
    const int* src; const int* dst; unsigned* bin; int* bcur;
    if (blockIdx.y == 0) { src = srcA; dst = dstA; bin = binA; bcur = bcurA; }
    else                 { src = srcB; dst = dstB; bin = binB; bcur = bcurB; }

    __shared__ int hist[32];
    __shared__ int base[32];
    const int tid = threadIdx.x;
    if (tid < 32) hist[tid] = 0;
    __syncthreads();

    const int e0 = blockIdx.x * BIN_CHUNK;
    unsigned pack[16];
    int rnk[16];
    int bkt[16];
    #pragma unroll
    for (int i = 0; i < 16; ++i) {
        int e = e0 + i * 256 + tid;
        if (e < N_EDGE) {
            unsigned d = (unsigned)dst[e];
            unsigned s = (unsigned)src[e];
            pack[i] = (d << 16) | s;
            bkt[i] = (int)(d >> BUCKET_SHIFT);
            rnk[i] = atomicAdd(&hist[bkt[i]], 1);
        } else {
            bkt[i] = -1;
        }
    }
    __syncthreads();
    if (tid < 32) {
        int c = hist[tid];
        base[tid] = (c > 0) ? atomicAdd(&bcur[tid], c) : 0;
    }
    __syncthreads();
    #pragma unroll
    for (int i = 0; i < 16; ++i) {
        if (bkt[i] >= 0) bin[base[bkt[i]] + rnk[i]] = pack[i];
    }
}

// ---------------------------------------------------------------------------
// Phase 2: within-bucket counting-sort scatter. Bucket k handled only by
// blocks with blockIdx.x%8 == k%8 (XCD affinity heuristic) -> per-XCD live
// scatter range ~2 MB, fits the 4 MB per-XCD L2 -> lines fill before evict.
// ---------------------------------------------------------------------------
__global__ __launch_bounds__(256) void scatter_kernel(
    const unsigned* __restrict__ binA, int* __restrict__ curA, int* __restrict__ srtA, const int* __restrict__ offA,
    const unsigned* __restrict__ binB, int* __restrict__ curB, int* __restrict__ srtB, const int* __restrict__ offB)
{
    const unsigned* bin; int* cur; int* srt; const int* off;
    if (blockIdx.y == 0) { bin = binA; cur = curA; srt = srtA; off = offA; }
    else                 { bin = binB; cur = curB; srt = srtB; off = offB; }

    const int b = blockIdx.x;     // 0 .. 8*SC_M-1
    const int x = b & 7;          // xcd group
    const int m = b >> 3;         // stripe within group
    for (int k = x; k < N_BUCKET; k += 8) {
        int bs = off[k << BUCKET_SHIFT];
        int hi = (k + 1) << BUCKET_SHIFT;
        int be = (hi <= N_NODE) ? off[hi] : off[N_NODE];
        for (int e = bs + m * 256 + threadIdx.x; e < be; e += SC_M * 256) {
            unsigned p = bin[e];
            int d = (int)(p >> 16);
            int s = (int)(p & 0xFFFFu);
            int pos = atomicAdd(&cur[d], 1);
            srt[pos] = s;
        }
    }
}

// ---------------------------------------------------------------------------
// Fallback path (old single-pass versions) if ws_size is too small.
// ---------------------------------------------------------------------------
__global__ __launch_bounds__(1024) void scan_kernel_old(
    const int* __restrict__ degI, int* __restrict__ offI, int* __restrict__ curI,
    const int* __restrict__ degU, int* __restrict__ offU, int* __restrict__ curU, int n)
{
    const int* deg = (blockIdx.x == 0) ? degI : degU;
    int* off       = (blockIdx.x == 0) ? offI : offU;
    int* cur       = (blockIdx.x == 0) ? curI : curU;

    __shared__ int s[1024];
    __shared__ int carry;
    if (threadIdx.x == 0) carry = 0;
    __syncthreads();

    for (int base = 0; base < n; base += 1024) {
        int i = base + threadIdx.x;
        int v = (i < n) ? deg[i] : 0;
        s[threadIdx.x] = v;
        __syncthreads();
        for (int o = 1; o < 1024; o <<= 1) {
            int t = (threadIdx.x >= o) ? s[threadIdx.x - o] : 0;
            __syncthreads();
            s[threadIdx.x] += t;
            __syncthreads();
        }
        int excl = s[threadIdx.x] - v;
        if (i < n) { int o = carry + excl; off[i] = o; cur[i] = o; }
        __syncthreads();
        if (threadIdx.x == 1023) carry += s[1023];
        __syncthreads();
    }
    if (threadIdx.x == 0) off[n] = carry;
}

__global__ void reorder_kernel_old(const int* __restrict__ rate_src, const int* __restrict__ rate_dst,
                                   const int* __restrict__ rev_src, const int* __restrict__ rev_dst,
                                   int* __restrict__ curI, int* __restrict__ curU,
                                   int* __restrict__ srtI, int* __restrict__ srtU, int n)
{
    for (int e = blockIdx.x * blockDim.x + threadIdx.x; e < n; e += gridDim.x * blockDim.x) {
        int p = atomicAdd(&curI[rate_dst[e]], 1);
        srtI[p] = rate_src[e];
        int q = atomicAdd(&curU[rev_dst[e]], 1);
        srtU[q] = rev_src[e];
    }
}

// ---------------------------------------------------------------------------
// Kernel 5: segment mean + add into loop term already in d_out.
// 16 lanes per dst node, float4 per lane (one 256B Wh row per edge iter).
// ---------------------------------------------------------------------------
__global__ __launch_bounds__(256) void aggregate_kernel(
    const float4* __restrict__ WhU,  // Wh_rev  (item-sourced msgs -> users)
    const float4* __restrict__ WhI,  // Wh_rate (user-sourced msgs -> items)
    const int* __restrict__ offU, const int* __restrict__ srtU,
    const int* __restrict__ offI, const int* __restrict__ srtI,
    float4* __restrict__ out)
{
    int g = blockIdx.x * 16 + (threadIdx.x >> 4);
    if (g >= N_USER + N_ITEM) return;
    const int lane = threadIdx.x & 15;

    const bool isUser = (g < N_USER);
    const int d = isUser ? g : g - N_USER;
    const float4* __restrict__ Wh = isUser ? WhU : WhI;
    const int* __restrict__ off   = isUser ? offU : offI;
    const int* __restrict__ srt   = isUser ? srtU : srtI;

    const int start = off[d];
    const int end   = off[d + 1];

    float4 acc = make_float4(0.f, 0.f, 0.f, 0.f);
    for (int e = start; e < end; ++e) {
        int s = srt[e];
        float4 v = Wh[(size_t)s * 16 + lane];
        acc.x += v.x; acc.y += v.y; acc.z += v.z; acc.w += v.w;
    }
    const int cnt = end - start;
    const float inv = 1.0f / (float)(cnt > 0 ? cnt : 1);

    float4* o = out + (size_t)g * 16 + lane;
    float4 curv = *o;
    curv.x += acc.x * inv; curv.y += acc.y * inv;
    curv.z += acc.z * inv; curv.w += acc.w * inv;
    *o = curv;
}

// ---------------------------------------------------------------------------
extern "C" void kernel_launch(void* const* d_in, const int* in_sizes, int n_in,
                              void* d_out, int out_size, void* d_ws, size_t ws_size,
                              hipStream_t stream)
{
    const float* user_feat = (const float*)d_in[0];
    const float* item_feat = (const float*)d_in[1];
    const int*   rate_src  = (const int*)d_in[2];
    const int*   rate_dst  = (const int*)d_in[3];
    const int*   rev_src   = (const int*)d_in[4];
    const int*   rev_dst   = (const int*)d_in[5];
    const float* W_rate    = (const float*)d_in[6];
    const float* b_rate    = (const float*)d_in[7];
    const float* W_rev     = (const float*)d_in[8];
    const float* b_rev     = (const float*)d_in[9];
    const float* loop_w    = (const float*)d_in[10];
    const float* h_bias    = (const float*)d_in[11];
    float* out = (float*)d_out;

    // workspace layout
    char* p = (char*)d_ws;
    float* Wh_rate = (float*)p; p += (size_t)N_USER * D * sizeof(float);
    float* Wh_rev  = (float*)p; p += (size_t)N_ITEM * D * sizeof(float);
    int* srtI = (int*)p; p += (size_t)N_EDGE * sizeof(int);
    int* srtU = (int*)p; p += (size_t)N_EDGE * sizeof(int);
    int* degI = (int*)p; p += (size_t)N_ITEM * sizeof(int);
    int* degU = (int*)p; p += (size_t)N_USER * sizeof(int);
    int* offI = (int*)p; p += (size_t)(N_ITEM + 1) * sizeof(int);
    int* offU = (int*)p; p += (size_t)(N_USER + 1) * sizeof(int);
    int* curI = (int*)p; p += (size_t)N_ITEM * sizeof(int);
    int* curU = (int*)p; p += (size_t)N_USER * sizeof(int);
    size_t base_bytes = (size_t)(p - (char*)d_ws);
    unsigned* binI = (unsigned*)p; p += (size_t)N_EDGE * sizeof(unsigned);
    unsigned* binU = (unsigned*)p; p += (size_t)N_EDGE * sizeof(unsigned);
    int* bsums = (int*)p; p += (size_t)(2 * NB) * sizeof(int);
    int* bcurI = (int*)p; p += 32 * sizeof(int);
    int* bcurU = (int*)p; p += 32 * sizeof(int);
    size_t need_bytes = (size_t)(p - (char*)d_ws);

    const bool fast_path = (ws_size >= need_bytes);

    // zero the degree histograms (degI/degU are contiguous)
    hipMemsetAsync(degI, 0, (size_t)(N_ITEM + N_USER) * sizeof(int), stream);

    // 1) dual GEMMs: Wh_etype into ws, loop term + bias into d_out
    gemm_dual<<<(N_USER + 15) / 16, 256, 0, stream>>>(
        user_feat, W_rate, b_rate, Wh_rate, loop_w, h_bias, out, N_USER);
    gemm_dual<<<(N_ITEM + 15) / 16, 256, 0, stream>>>(
        item_feat, W_rev, b_rev, Wh_rev, loop_w, h_bias, out + (size_t)N_USER * D, N_ITEM);

    // 2) degree histograms
    hist_kernel<<<1024, 256, 0, stream>>>(rate_dst, rev_dst, degI, degU, N_EDGE);

    if (fast_path) {
        // 3) parallel exclusive scan -> off, cur, bucket cursors
        scanA<<<dim3(NB, 2), 1024, 0, stream>>>(degI, offI, degU, offU, bsums);
        scanB<<<1, 64, 0, stream>>>(bsums, offI, offU);
        scanC<<<dim3(NB, 2), 1024, 0, stream>>>(offI, curI, bcurI, offU, curU, bcurU, bsums);

        // 4a) bin edges by dst bucket (packed dst|src)
        bin_kernel<<<dim3((N_EDGE + BIN_CHUNK - 1) / BIN_CHUNK, 2), 256, 0, stream>>>(
            rate_src, rate_dst, binI, bcurI,
            rev_src,  rev_dst,  binU, bcurU);

        // 4b) within-bucket scatter (L2-resident target windows)
        scatter_kernel<<<dim3(8 * SC_M, 2), 256, 0, stream>>>(
            binI, curI, srtI, offI,
            binU, curU, srtU, offU);
    } else {
        // fallback: old single-pass path
        scan_kernel_old<<<2, 1024, 0, stream>>>(degI, offI, curI, degU, offU, curU, N_ITEM);
        reorder_kernel_old<<<1024, 256, 0, stream>>>(
            rate_src, rate_dst, rev_src, rev_dst, curI, curU, srtI, srtU, N_EDGE);
    }

    // 5) segment mean + loop-term add
    aggregate_kernel<<<(N_USER + N_ITEM + 15) / 16, 256, 0, stream>>>(
        (const float4*)Wh_rev, (const float4*)Wh_rate, offU, srtU, offI, srtI,
        (float4*)out);
    (void)base_bytes; (void)in_sizes; (void)n_in; (void)out_size;
}